// Round 7
// baseline (64.881 us; speedup 1.0000x reference)
//
#include <hip/hip_runtime.h>
#include <hip/hip_bf16.h>

typedef unsigned short ushort_t;
typedef __attribute__((ext_vector_type(8))) short s16x8;
typedef __attribute__((ext_vector_type(4))) float f32x4;

#define NB 8192
#define ND 128
#define KE 192              // 128 emb cols + 64 one-hot label cols
#define WROWS 64            // rows per wave
#define BMR 256             // rows per block (4 waves)
#define CHUNK 512           // cols per block
#define NC16 (CHUNK/16)     // 32 fold steps of 16 cols
#define EPS 1e-8f
#define MARGIN 1.0f

__device__ __forceinline__ unsigned f2u(float f) {
    unsigned u = __float_as_uint(f);
    return (u & 0x80000000u) ? ~u : (u | 0x80000000u);
}
__device__ __forceinline__ float u2f(unsigned u) {
    return (u & 0x80000000u) ? __uint_as_float(u & 0x7fffffffu) : __uint_as_float(~u);
}

// ---- kernel 1: f32 -> bf16 + one-hot(+1.0) label cols + init atomics ----
__global__ void prep_kernel(const float* __restrict__ E,
                            const int* __restrict__ labels,
                            ushort_t* __restrict__ Eb,
                            unsigned* __restrict__ posU,
                            unsigned* __restrict__ negU) {
    const int tid  = threadIdx.x;
    const int lane = tid & 63;
    const int row  = blockIdx.x * 4 + (tid >> 6);

    const float2 v = reinterpret_cast<const float2*>(E + (size_t)row * ND)[lane];
    __hip_bfloat16 b0 = __float2bfloat16(v.x);
    __hip_bfloat16 b1 = __float2bfloat16(v.y);
    uint pk = (uint)*reinterpret_cast<ushort_t*>(&b0)
            | ((uint)*reinterpret_cast<ushort_t*>(&b1) << 16);
    uint* rowp = reinterpret_cast<uint*>(Eb + (size_t)row * KE);
    rowp[lane] = pk;                       // emb cols 0..127

    if (lane < 32) {                       // one-hot cols 128..191, value +1.0 bf16
        const int lab = labels[row];
        const int c0 = lane * 2, c1 = lane * 2 + 1;
        uint e = (uint)((lab == c0) ? 0x3F80u : 0u)
               | (((lab == c1) ? 0x3F80u : 0u) << 16);
        rowp[64 + lane] = e;
    }

    const int gid = blockIdx.x * 256 + tid;
    if (gid < NB) {
        posU[gid] = f2u(__builtin_inff());    // running min u
        negU[gid] = f2u(-__builtin_inff());   // running max u
    }
}

// ---- kernel 2: barrier-free; B frags straight from L1/L2; u = dot - 8*eq ----
__global__ __launch_bounds__(256, 2) void triplet_gemm(
        const ushort_t* __restrict__ Eb,
        const int* __restrict__ labels,
        unsigned* __restrict__ posU,
        unsigned* __restrict__ negU) {
    const int tid = threadIdx.x, lane = tid & 63, w = tid >> 6;
    const int fr = lane & 15, fg = lane >> 4;
    const int wrow = blockIdx.x * BMR + w * WROWS;
    const int colBase = blockIdx.y * CHUNK;

    // A fragments: emb part from global (L2-hit), one-hot part synthesized (-8.0)
    s16x8 a[6][4];
    #pragma unroll
    for (int ks = 0; ks < 4; ++ks)
        #pragma unroll
        for (int mi = 0; mi < 4; ++mi)
            a[ks][mi] = *reinterpret_cast<const s16x8*>(
                Eb + (size_t)(wrow + mi * 16 + fr) * KE + ks * 32 + fg * 8);
    {
        int labv[4];
        #pragma unroll
        for (int mi = 0; mi < 4; ++mi) labv[mi] = labels[wrow + mi * 16 + fr];
        #pragma unroll
        for (int ks = 4; ks < 6; ++ks)
            #pragma unroll
            for (int mi = 0; mi < 4; ++mi) {
                s16x8 t{};
                #pragma unroll
                for (int j = 0; j < 8; ++j) {
                    const int c = (ks - 4) * 32 + fg * 8 + j;
                    t[j] = (labv[mi] == c) ? (short)0xC100 : (short)0;
                }
                a[ks][mi] = t;
            }
    }

    const float PINF = __builtin_inff(), NINF = -__builtin_inff();
    f32x4 pv[4], nv[4];
    #pragma unroll
    for (int mi = 0; mi < 4; ++mi) {
        pv[mi] = f32x4{PINF, PINF, PINF, PINF};
        nv[mi] = f32x4{NINF, NINF, NINF, NINF};
    }
    const f32x4 zf = {0.f, 0.f, 0.f, 0.f};

    const ushort_t* bbase = Eb + (size_t)(colBase + fr) * KE + fg * 8;

    auto loadB = [&](s16x8* b, int c) {
        const ushort_t* p = bbase + (size_t)c * 16 * KE;
        #pragma unroll
        for (int ks = 0; ks < 6; ++ks)
            b[ks] = *reinterpret_cast<const s16x8*>(p + ks * 32);
    };
    auto fold = [&](const s16x8* b) {
        f32x4 acc[4];
        #pragma unroll
        for (int mi = 0; mi < 4; ++mi)
            acc[mi] = __builtin_amdgcn_mfma_f32_16x16x32_bf16(a[0][mi], b[0], zf, 0, 0, 0);
        #pragma unroll
        for (int ks = 1; ks < 6; ++ks)
            #pragma unroll
            for (int mi = 0; mi < 4; ++mi)
                acc[mi] = __builtin_amdgcn_mfma_f32_16x16x32_bf16(a[ks][mi], b[ks], acc[mi], 0, 0, 0);
        #pragma unroll
        for (int mi = 0; mi < 4; ++mi)
            #pragma unroll
            for (int reg = 0; reg < 4; ++reg) {
                pv[mi][reg] = fminf(pv[mi][reg], acc[mi][reg]);
                nv[mi][reg] = fmaxf(nv[mi][reg], acc[mi][reg]);
            }
    };

    s16x8 bX[6], bY[6];
    loadB(bX, 0);
    #pragma unroll 1
    for (int c = 0; c < NC16; c += 2) {
        loadB(bY, c + 1);
        fold(bX);
        if (c + 2 < NC16) loadB(bX, c + 2);
        fold(bY);
    }

    // epilogue: reduce across 16 fr-lanes, 2 atomics per row from fr==0 lanes
    #pragma unroll
    for (int mi = 0; mi < 4; ++mi)
        #pragma unroll
        for (int reg = 0; reg < 4; ++reg) {
            float p = pv[mi][reg], n = nv[mi][reg];
            #pragma unroll
            for (int off = 1; off < 16; off <<= 1) {
                p = fminf(p, __shfl_xor(p, off, 64));
                n = fmaxf(n, __shfl_xor(n, off, 64));
            }
            if (fr == 0) {
                const int grow = wrow + mi * 16 + fg * 4 + reg;
                atomicMin(&posU[grow], f2u(p));
                atomicMax(&negU[grow], f2u(n));
            }
        }
}

// ---- kernel 3: single-block deterministic finalize ----
__global__ void finalize_kernel(const unsigned* __restrict__ posU,
                                const unsigned* __restrict__ negU,
                                float* __restrict__ out) {
    __shared__ float sl[16], sc[16];
    const int tid = threadIdx.x, lane = tid & 63, w = tid >> 6;

    float lsum = 0.f, csum = 0.f;
    #pragma unroll
    for (int k = 0; k < NB / 1024; ++k) {
        const int i = k * 1024 + tid;
        float pMin = u2f(posU[i]);       // min u; positives at dot-8 (self = -7)
        float nMax = u2f(negU[i]);       // max u; negatives at dot
        bool valid = (nMax > -2.0f) && (pMin < -6.0f);
        float pd = sqrtf(fmaxf(2.0f - 2.0f * (pMin + 8.0f), 0.f) + EPS);
        float nd = sqrtf(fmaxf(2.0f - 2.0f * nMax, 0.f) + EPS);
        float l  = fmaxf(pd - nd + MARGIN, 0.f);
        if (valid) { lsum += l; csum += 1.f; }
    }
    #pragma unroll
    for (int off = 32; off; off >>= 1) {
        lsum += __shfl_down(lsum, off, 64);
        csum += __shfl_down(csum, off, 64);
    }
    if (lane == 0) { sl[w] = lsum; sc[w] = csum; }
    __syncthreads();
    if (tid == 0) {
        float L = 0.f, C = 0.f;
        #pragma unroll
        for (int k = 0; k < 16; ++k) { L += sl[k]; C += sc[k]; }
        out[0] = (C > 0.f) ? (L / C) : 0.f;
        out[1] = C;
    }
}

extern "C" void kernel_launch(void* const* d_in, const int* in_sizes, int n_in,
                              void* d_out, int out_size, void* d_ws, size_t ws_size,
                              hipStream_t stream) {
    const float* E      = (const float*)d_in[0];
    const int*   labels = (const int*)d_in[1];
    float*       out    = (float*)d_out;

    char* ws = (char*)d_ws;
    size_t off = 0;
    ushort_t* Eb   = (ushort_t*)(ws + off);  off += (size_t)NB * KE * 2;   // 3 MiB
    unsigned* posU = (unsigned*)(ws + off);  off += (size_t)NB * 4;        // 32 KiB
    unsigned* negU = (unsigned*)(ws + off);  off += (size_t)NB * 4;        // 32 KiB

    prep_kernel<<<NB / 4, 256, 0, stream>>>(E, labels, Eb, posU, negU);

    dim3 grid(NB / BMR, NB / CHUNK);
    triplet_gemm<<<grid, 256, 0, stream>>>(Eb, labels, posU, negU);

    finalize_kernel<<<1, 1024, 0, stream>>>(posU, negU, out);
}

// Round 8
// 53.531 us; speedup vs baseline: 1.2120x; 1.2120x over previous
//
#include <hip/hip_runtime.h>
#include <hip/hip_bf16.h>

typedef unsigned short ushort_t;
typedef __attribute__((ext_vector_type(8))) short s16x8;
typedef __attribute__((ext_vector_type(4))) float f32x4;

#define NB 8192
#define ND 128
#define ROWB 256            // bytes per row (128 bf16)
#define WROWS 64            // rows per wave
#define BMR 256             // rows per block (4 waves)
#define WCOLS 512           // cols per wave (= cols per block)
#define NSTEP 32            // WCOLS / 16
#define EPS 1e-8f
#define MARGIN 1.0f

__device__ __forceinline__ unsigned f2u(float f) {
    unsigned u = __float_as_uint(f);
    return (u & 0x80000000u) ? ~u : (u | 0x80000000u);
}
__device__ __forceinline__ float u2f(unsigned u) {
    return (u & 0x80000000u) ? __uint_as_float(u & 0x7fffffffu) : __uint_as_float(~u);
}

typedef const __attribute__((address_space(1))) void* gptr_t;
typedef __attribute__((address_space(3))) void* lptr_t;
__device__ __forceinline__ void gll16(const void* g, void* l) {
    __builtin_amdgcn_global_load_lds((gptr_t)g, (lptr_t)l, 16, 0, 0);
}

// ---- kernel 1: f32 -> bf16 + init atomic sentinels ----
__global__ void prep_kernel(const float* __restrict__ E,
                            ushort_t* __restrict__ Ebf,
                            unsigned* __restrict__ posU,
                            unsigned* __restrict__ negU) {
    const int tid  = threadIdx.x;
    const int lane = tid & 63;
    const int row  = blockIdx.x * 4 + (tid >> 6);

    const float2 v = reinterpret_cast<const float2*>(E + (size_t)row * ND)[lane];
    __hip_bfloat16 b0 = __float2bfloat16(v.x);
    __hip_bfloat16 b1 = __float2bfloat16(v.y);
    uint pk = (uint)*reinterpret_cast<ushort_t*>(&b0)
            | ((uint)*reinterpret_cast<ushort_t*>(&b1) << 16);
    reinterpret_cast<uint*>(Ebf + (size_t)row * ND)[lane] = pk;

    const int gid = blockIdx.x * 256 + tid;
    if (gid < NB) {
        posU[gid] = f2u(__builtin_inff());    // running min dot over positives
        negU[gid] = f2u(-__builtin_inff());   // running max dot over negatives
    }
}

// ---- kernel 2: wave-private LDS staging, zero inter-wave barriers ----
__global__ __launch_bounds__(256, 1) void triplet_gemm(
        const ushort_t* __restrict__ Ebf,
        const int* __restrict__ labels,
        unsigned* __restrict__ posU,
        unsigned* __restrict__ negU) {
    __shared__ __align__(16) ushort_t buf[4][2][16 * ND];   // 4 waves x 2 x 4 KB
    __shared__ __align__(16) int ldsLab[WCOLS];             // 2 KB

    const int tid = threadIdx.x, lane = tid & 63, w = tid >> 6;
    const int fr = lane & 15, fg = lane >> 4;
    const int wrow = blockIdx.x * BMR + w * WROWS;
    const int colBase = blockIdx.y * WCOLS;

    // chunk labels -> LDS (the only cross-wave shared data)
    ldsLab[tid]       = labels[colBase + tid];
    ldsLab[tid + 256] = labels[colBase + 256 + tid];

    // A fragments: 64 rows x K=128 from global (L2-hit), 64 VGPR
    s16x8 a[4][4];
    #pragma unroll
    for (int ks = 0; ks < 4; ++ks)
        #pragma unroll
        for (int mi = 0; mi < 4; ++mi)
            a[ks][mi] = *reinterpret_cast<const s16x8*>(
                Ebf + (size_t)(wrow + mi * 16 + fr) * ND + ks * 32 + fg * 8);

    int labR[4][4];
    #pragma unroll
    for (int mi = 0; mi < 4; ++mi)
        #pragma unroll
        for (int reg = 0; reg < 4; ++reg)
            labR[mi][reg] = labels[wrow + mi * 16 + fg * 4 + reg];

    // staging source offsets (pre-swizzled): chunk c=it*64+lane -> row r, slot s
    int srcOff[4];
    #pragma unroll
    for (int it = 0; it < 4; ++it) {
        const int r = it * 4 + (lane >> 4), s = lane & 15;
        srcOff[it] = r * ROWB + ((s ^ (r & 7)) << 4);
    }
    // swizzled read offsets: lane reads B-row fr, 16B slot (ks*4+fg)^(fr&7)
    int rdOff[4];
    #pragma unroll
    for (int ks = 0; ks < 4; ++ks)
        rdOff[ks] = fr * ROWB + ((((ks * 4) + fg) ^ (fr & 7)) << 4);

    auto stage = [&](int bi, int step) {
        const char* g = (const char*)Ebf + (size_t)(colBase + step * 16) * ROWB;
        char* l = (char*)&buf[w][bi][0];
        #pragma unroll
        for (int it = 0; it < 4; ++it)
            gll16(g + srcOff[it], l + it * 1024 + (lane << 4));
    };

    __syncthreads();     // ldsLab ready (only barrier in the kernel)
    stage(0, 0);

    const float PINF = __builtin_inff(), NINF = -__builtin_inff();
    f32x4 pv[4], nv[4];
    #pragma unroll
    for (int mi = 0; mi < 4; ++mi) {
        pv[mi] = f32x4{PINF, PINF, PINF, PINF};
        nv[mi] = f32x4{NINF, NINF, NINF, NINF};
    }
    const f32x4 zf = {0.f, 0.f, 0.f, 0.f};

    #pragma unroll 1
    for (int step = 0; step < NSTEP; ++step) {
        if (step + 1 < NSTEP) {
            stage((step + 1) & 1, step + 1);
            asm volatile("s_waitcnt vmcnt(4)" ::: "memory");   // step's 4 landed; next in flight
        } else {
            asm volatile("s_waitcnt vmcnt(0)" ::: "memory");
        }
        const char* cp = (const char*)&buf[w][step & 1][0];
        const int labC = ldsLab[step * 16 + fr];

        s16x8 b[4];
        #pragma unroll
        for (int ks = 0; ks < 4; ++ks)
            b[ks] = *reinterpret_cast<const s16x8*>(cp + rdOff[ks]);

        f32x4 acc[4];
        #pragma unroll
        for (int mi = 0; mi < 4; ++mi)
            acc[mi] = __builtin_amdgcn_mfma_f32_16x16x32_bf16(a[0][mi], b[0], zf, 0, 0, 0);
        #pragma unroll
        for (int ks = 1; ks < 4; ++ks)
            #pragma unroll
            for (int mi = 0; mi < 4; ++mi)
                acc[mi] = __builtin_amdgcn_mfma_f32_16x16x32_bf16(a[ks][mi], b[ks], acc[mi], 0, 0, 0);

        #pragma unroll
        for (int mi = 0; mi < 4; ++mi)
            #pragma unroll
            for (int reg = 0; reg < 4; ++reg) {
                float d = acc[mi][reg];
                bool eq = (labR[mi][reg] == labC);
                pv[mi][reg] = fminf(pv[mi][reg], eq ? d : PINF);
                nv[mi][reg] = fmaxf(nv[mi][reg], eq ? NINF : d);
            }
    }

    // epilogue: 16-lane reduce, 2 atomics per row from fr==0 lanes
    #pragma unroll
    for (int mi = 0; mi < 4; ++mi)
        #pragma unroll
        for (int reg = 0; reg < 4; ++reg) {
            float p = pv[mi][reg], n = nv[mi][reg];
            #pragma unroll
            for (int off = 1; off < 16; off <<= 1) {
                p = fminf(p, __shfl_xor(p, off, 64));
                n = fmaxf(n, __shfl_xor(n, off, 64));
            }
            if (fr == 0) {
                const int grow = wrow + mi * 16 + fg * 4 + reg;
                atomicMin(&posU[grow], f2u(p));
                atomicMax(&negU[grow], f2u(n));
            }
        }
}

// ---- kernel 3: single-block deterministic finalize (|e|^2 == 1) ----
__global__ void finalize_kernel(const unsigned* __restrict__ posU,
                                const unsigned* __restrict__ negU,
                                float* __restrict__ out) {
    __shared__ float sl[16], sc[16];
    const int tid = threadIdx.x, lane = tid & 63, w = tid >> 6;

    float lsum = 0.f, csum = 0.f;
    #pragma unroll
    for (int k = 0; k < NB / 1024; ++k) {
        const int i = k * 1024 + tid;
        float pMin = u2f(posU[i]);       // min dot over same-label
        float nMax = u2f(negU[i]);       // max dot over diff-label
        bool valid = (pMin < 2.0f) && (nMax > -2.0f);
        float pd = sqrtf(fmaxf(2.0f - 2.0f * pMin, 0.f) + EPS);
        float nd = sqrtf(fmaxf(2.0f - 2.0f * nMax, 0.f) + EPS);
        float l  = fmaxf(pd - nd + MARGIN, 0.f);
        if (valid) { lsum += l; csum += 1.f; }
    }
    #pragma unroll
    for (int off = 32; off; off >>= 1) {
        lsum += __shfl_down(lsum, off, 64);
        csum += __shfl_down(csum, off, 64);
    }
    if (lane == 0) { sl[w] = lsum; sc[w] = csum; }
    __syncthreads();
    if (tid == 0) {
        float L = 0.f, C = 0.f;
        #pragma unroll
        for (int k = 0; k < 16; ++k) { L += sl[k]; C += sc[k]; }
        out[0] = (C > 0.f) ? (L / C) : 0.f;
        out[1] = C;
    }
}

extern "C" void kernel_launch(void* const* d_in, const int* in_sizes, int n_in,
                              void* d_out, int out_size, void* d_ws, size_t ws_size,
                              hipStream_t stream) {
    const float* E      = (const float*)d_in[0];
    const int*   labels = (const int*)d_in[1];
    float*       out    = (float*)d_out;

    char* ws = (char*)d_ws;
    size_t off = 0;
    ushort_t* Ebf  = (ushort_t*)(ws + off);  off += (size_t)NB * ND * 2;   // 2 MiB
    unsigned* posU = (unsigned*)(ws + off);  off += (size_t)NB * 4;        // 32 KiB
    unsigned* negU = (unsigned*)(ws + off);  off += (size_t)NB * 4;        // 32 KiB

    prep_kernel<<<NB / 4, 256, 0, stream>>>(E, Ebf, posU, negU);

    dim3 grid(NB / BMR, NB / WCOLS);
    triplet_gemm<<<grid, 256, 0, stream>>>(Ebf, labels, posU, negU);

    finalize_kernel<<<1, 1024, 0, stream>>>(posU, negU, out);
}